// Round 10
// baseline (585.481 us; speedup 1.0000x reference)
//
#include <hip/hip_runtime.h>

// NOTE: reference uses finfo(f32).min = -3.4028e38, which rounds to -inf in
// bf16 — the harness compares through bf16, and (-inf) - (-inf) = nan fails.
// -3.0e38 is finite in bf16, semantically identical through softmax/masking.
#define NEGF (-3.0e38f)

// problem sizes
#define BB 4
#define LQQ 64
#define EE_N 512
#define RR 32
#define HH 768

// workspace offsets (floats)
#define WS_QBAR 0
#define WS_Q    3072
#define WS_QD   6144
#define WS_WR1C 6656
#define WS_D0   7424
#define WS_D1   8192
#define WS_C0   8960
#define WS_C1   598784
#define WS_EEA  1188608
#define WS_EEB  2761472
#define WS_EEW  4334336
#define WS_W    5907200
#define WS_AGG  5972736
#define WS_SDOT 7545600
#define WS_CKT0 7547648
#define WS_CKT1 7842560
#define WS_PWT  8137472
#define WS_W0BT 8432384
#define WS_W1BT 8727296
#define WS_U0TT 9022208
#define WS_U0BT 9317120
#define WS_U1TT 9612032
#define WS_U1BT 9906944
#define WS_M0TT 10201856
#define WS_M1TT 10496768
#define WS_RELBF 10791680
// big path total: 10791680 + 25165824 = 35957504 floats = 143.8 MB
#define WS_NEED_BYTES 143830016ull

typedef __attribute__((ext_vector_type(8))) short short8v;
typedef __attribute__((ext_vector_type(4))) short short4v;
typedef __attribute__((ext_vector_type(4))) float f32x4;

#define GLOAD_LDS16(gp, lp) __builtin_amdgcn_global_load_lds( \
    (const __attribute__((address_space(1))) void*)(gp), \
    (__attribute__((address_space(3))) void*)(lp), 16, 0, 0)

__device__ __forceinline__ float gelu_erf(float x) {
    return 0.5f * x * (1.0f + erff(x * 0.70710678118654752f));
}

__device__ __forceinline__ unsigned short f2bf(float f) {
    unsigned int u = __float_as_uint(f);
    unsigned int r = (u + 0x7fffu + ((u >> 16) & 1u)) >> 16;   // RNE
    return (unsigned short)r;
}

__device__ __forceinline__ float bf2f(unsigned short h) {
    return __uint_as_float(((unsigned int)h) << 16);
}

// ---------------------------------------------------------------- qbar
__global__ void k_qbar(const float* __restrict__ QE, const float* __restrict__ QM,
                       float* __restrict__ qbar) {
    int b = blockIdx.x;
    int tid = threadIdx.x;
    float msum = 0.f;
    for (int l = 0; l < LQQ; ++l) msum += QM[b*LQQ + l];
    for (int h = tid; h < HH; h += 256) {
        float s = 0.f;
        for (int l = 0; l < LQQ; ++l)
            s += QM[b*LQQ + l] * QE[((size_t)(b*LQQ + l))*HH + h];
        qbar[b*HH + h] = s / msum;
    }
}

// ---------------------------------------------------------------- small vectors (wave-parallel)
__global__ void k_small2(const float* __restrict__ RW, const float* __restrict__ RB,
                         const float* __restrict__ RSW, const float* __restrict__ RSB,
                         const float* __restrict__ q, float* __restrict__ wr1c,
                         float* __restrict__ qd) {
    const int wid = threadIdx.x >> 6, lane = threadIdx.x & 63;
    const int blk = blockIdx.x;
    if (blk < 192) {
        int row = blk*4 + wid;
        const float* a = RW + (size_t)row*HH;
        float acc = 0.f;
        #pragma unroll
        for (int p = 0; p < 3; ++p) {
            int i4 = (p*64 + lane) << 2;
            float4 x = *(const float4*)(a + i4);
            float4 w = *(const float4*)(RSW + i4);
            acc += x.x*w.x + x.y*w.y + x.z*w.z + x.w*w.w;
        }
        for (int off = 32; off; off >>= 1) acc += __shfl_xor(acc, off);
        if (lane == 0) wr1c[row] = acc;
    } else {
        float acc = 0.f, acc2 = 0.f;
        const float* src = q + wid*HH;
        #pragma unroll
        for (int p = 0; p < 3; ++p) {
            int i4 = (p*64 + lane) << 2;
            float4 x = *(const float4*)(src + i4);
            float4 w = *(const float4*)(RSW + HH + i4);
            acc += x.x*w.x + x.y*w.y + x.z*w.z + x.w*w.w;
            if (wid == 0) {
                float4 rb = *(const float4*)(RB + i4);
                float4 w0 = *(const float4*)(RSW + i4);
                acc2 += rb.x*w0.x + rb.y*w0.y + rb.z*w0.z + rb.w*w0.w;
            }
        }
        for (int off = 32; off; off >>= 1) { acc += __shfl_xor(acc, off); acc2 += __shfl_xor(acc2, off); }
        if (lane == 0) qd[wid] = acc;
        if (wid == 0 && lane == 0) qd[BB] = acc2 + RSB[0];
    }
}

// ---------------------------------------------------------------- dk via transposed bf16 weights
__global__ void k_dk2(const unsigned short* __restrict__ M0tT,
                      const unsigned short* __restrict__ M1tT,
                      const float* __restrict__ RB, const float* __restrict__ MB,
                      float* __restrict__ d0, float* __restrict__ d1) {
    const int gw = blockIdx.x*4 + (threadIdx.x >> 6);   // 0..1535
    const int lane = threadIdx.x & 63;
    const int hop = gw >= HH;
    const int n = hop ? gw - HH : gw;
    const unsigned short* row = (hop ? M1tT : M0tT) + (size_t)n*HH;
    float s = 0.f;
    #pragma unroll
    for (int p = 0; p < 3; ++p) {
        int i4 = (p*64 + lane) << 2;
        const unsigned short* hp = row + i4;
        float4 rv = *(const float4*)(RB + i4);
        s += bf2f(hp[0])*rv.x + bf2f(hp[1])*rv.y + bf2f(hp[2])*rv.z + bf2f(hp[3])*rv.w;
    }
    for (int off = 32; off; off >>= 1) s += __shfl_xor(s, off);
    if (lane == 0) (hop ? d1 : d0)[n] = s + MB[hop*HH + n];
}

// ---------------------------------------------------------------- generic GEMM f32 (tiny M only)
__global__ __launch_bounds__(256) void gemm_f32(
    const float* __restrict__ A1, const float* __restrict__ W1,
    const float* __restrict__ bias, float* __restrict__ C,
    int M, int N, int K, int act)
{
    __shared__ float Asm[16][68];
    __shared__ float Bs[16][68];
    const int tid = threadIdx.x;
    const int n0 = blockIdx.x * 64;
    const int m0 = blockIdx.y * 64;
    const int tm = tid >> 4;
    const int tn = tid & 15;
    float acc[4][4] = {};
    for (int kk = 0; kk < K; kk += 16) {
        const int ar = tid >> 2;
        const int ak = (tid & 3) << 2;
        float4 av = make_float4(0.f, 0.f, 0.f, 0.f);
        if (m0 + ar < M) av = *(const float4*)(A1 + (size_t)(m0 + ar)*K + kk + ak);
        const int br = tid >> 4;
        const int bc = (tid & 15) << 2;
        float4 bv = *(const float4*)(W1 + (size_t)(kk + br)*N + n0 + bc);
        __syncthreads();
        Asm[ak+0][ar] = av.x; Asm[ak+1][ar] = av.y;
        Asm[ak+2][ar] = av.z; Asm[ak+3][ar] = av.w;
        *(float4*)&Bs[br][bc] = bv;
        __syncthreads();
        #pragma unroll
        for (int k = 0; k < 16; ++k) {
            float4 a4 = *(const float4*)&Asm[k][tm << 2];
            float4 b4 = *(const float4*)&Bs[k][tn << 2];
            float a[4] = {a4.x, a4.y, a4.z, a4.w};
            float b[4] = {b4.x, b4.y, b4.z, b4.w};
            #pragma unroll
            for (int i = 0; i < 4; ++i)
                #pragma unroll
                for (int j = 0; j < 4; ++j)
                    acc[i][j] = fmaf(a[i], b[j], acc[i][j]);
        }
    }
    float4 bb = make_float4(0.f, 0.f, 0.f, 0.f);
    if (bias) bb = *(const float4*)(bias + n0 + (tn << 2));
    float bbv[4] = {bb.x, bb.y, bb.z, bb.w};
    #pragma unroll
    for (int i = 0; i < 4; ++i) {
        int m = m0 + (tm << 2) + i;
        if (m >= M) break;
        #pragma unroll
        for (int j = 0; j < 4; ++j) {
            float v = acc[i][j] + bbv[j];
            if (act) v = gelu_erf(v);
            C[(size_t)m*N + n0 + (tn << 2) + j] = v;
        }
    }
}

// ---------------------------------------------------------------- f32 [K][N] -> bf16 [N][K]
__global__ void k_ckt(const float* __restrict__ Ck, unsigned short* __restrict__ CkT) {
    __shared__ float t[32][33];
    const int k0 = blockIdx.x * 32, n0 = blockIdx.y * 32;
    const int tid = threadIdx.x;   // 256
    {
        int r = tid >> 3;
        int c4 = (tid & 7) << 2;
        float4 v = *(const float4*)(Ck + (size_t)(k0 + r)*HH + n0 + c4);
        t[r][c4+0] = v.x; t[r][c4+1] = v.y; t[r][c4+2] = v.z; t[r][c4+3] = v.w;
    }
    __syncthreads();
    {
        int n = tid >> 3;
        int k4 = (tid & 7) << 2;
        unsigned short o[4];
        #pragma unroll
        for (int j = 0; j < 4; ++j) o[j] = f2bf(t[k4+j][n]);
        *(uint2*)(CkT + (size_t)(n0 + n)*HH + k0 + k4) = *(const uint2*)o;
    }
}

// batched version for the 9 input weight matrices
struct WPairs { const float* s[9]; unsigned short* d[9]; };
__global__ void k_w2bf(WPairs p) {
    __shared__ float t[32][33];
    const float* __restrict__ Ck = p.s[blockIdx.z];
    unsigned short* __restrict__ CkT = p.d[blockIdx.z];
    const int k0 = blockIdx.x * 32, n0 = blockIdx.y * 32;
    const int tid = threadIdx.x;
    {
        int r = tid >> 3;
        int c4 = (tid & 7) << 2;
        float4 v = *(const float4*)(Ck + (size_t)(k0 + r)*HH + n0 + c4);
        t[r][c4+0] = v.x; t[r][c4+1] = v.y; t[r][c4+2] = v.z; t[r][c4+3] = v.w;
    }
    __syncthreads();
    {
        int n = tid >> 3;
        int k4 = (tid & 7) << 2;
        unsigned short o[4];
        #pragma unroll
        for (int j = 0; j < 4; ++j) o[j] = f2bf(t[k4+j][n]);
        *(uint2*)(CkT + (size_t)(n0 + n)*HH + k0 + k4) = *(const uint2*)o;
    }
}

// ---------------------------------------------------------------- rel f32 -> bf16 + fused logit
__global__ __launch_bounds__(256) void k_cvt(
    const float* __restrict__ rel, const float* __restrict__ wr1c,
    const float* __restrict__ qd, const float* __restrict__ am,
    unsigned short* __restrict__ relbf, float* __restrict__ logit) {
    const int wid = threadIdx.x >> 6, lane = threadIdx.x & 63;
    const long row = (long)blockIdx.x*4 + wid;   // < 65536
    const float* a = rel + row*HH;
    unsigned short* o = relbf + row*HH;
    float acc = 0.f;
    #pragma unroll
    for (int p = 0; p < 3; ++p) {
        int i4 = (p*64 + lane) << 2;
        float4 x = *(const float4*)(a + i4);
        float4 wv = *(const float4*)(wr1c + i4);
        acc += x.x*wv.x + x.y*wv.y + x.z*wv.z + x.w*wv.w;
        unsigned short h[4] = {f2bf(x.x), f2bf(x.y), f2bf(x.z), f2bf(x.w)};
        *(uint2*)(o + i4) = *(const uint2*)h;
    }
    for (int off = 32; off; off >>= 1) acc += __shfl_xor(acc, off);
    if (lane == 0) {
        int b = (int)(row >> 14);
        logit[row] = acc + qd[b] + qd[BB] + (1.0f - am[row]) * NEGF;
    }
}

// ---------------------------------------------------------------- softmax over R=32
__global__ void k_softmax(const float* __restrict__ logit, const float* __restrict__ am,
                          float* __restrict__ weight) {
    int row = blockIdx.x;
    int lane = threadIdx.x;
    if (lane < 32) {
        float l = logit[row*RR + lane];
        float m = l;
        for (int off = 16; off; off >>= 1) m = fmaxf(m, __shfl_xor(m, off, 32));
        float e = expf(l - m);
        float s = e;
        for (int off = 16; off; off >>= 1) s += __shfl_xor(s, off, 32);
        weight[row*RR + lane] = am[row*RR + lane] * e / s;
    }
}

// ---------------------------------------------------------------- tiled bf16 MFMA GEMM
template<int BM>
__global__ __launch_bounds__(256) void gemm_bf16(
    const float* __restrict__ A1, const unsigned short* __restrict__ W1T,
    const float* __restrict__ A2, const unsigned short* __restrict__ W2T,
    const float* __restrict__ bias, float* __restrict__ C, int act)
{
    constexpr int FM = BM / 32;             // m-frags per wave (min 1)
    constexpr int AC = BM / 16;             // A 16-row chunks
    __shared__ alignas(16) unsigned short As[BM*64];
    __shared__ alignas(16) unsigned short Bs[128*64];
    const int tid = threadIdx.x;
    const int n0 = blockIdx.x * 128;
    const int m0 = blockIdx.y * BM;
    const int w = tid >> 6, lane = tid & 63;
    const int wm = w >> 1, wn = w & 1;
    const int l15 = lane & 15, l4 = lane >> 4;
    const int am_row = tid >> 4;
    const int am_col = (tid & 15) * 4;
    const int bm_row = tid >> 3;
    const int bm_col = (tid & 7) * 8;
    f32x4 acc[FM][4];
    #pragma unroll
    for (int i = 0; i < FM; ++i)
        #pragma unroll
        for (int j = 0; j < 4; ++j) acc[i][j] = (f32x4){0.f,0.f,0.f,0.f};
    const int nPass = (A2 != nullptr) ? 2 : 1;
    for (int pass = 0; pass < nPass; ++pass) {
        const float* __restrict__ A = pass ? A2 : A1;
        const unsigned short* __restrict__ WT = pass ? W2T : W1T;
        for (int k0 = 0; k0 < HH; k0 += 64) {
            float4 av[AC];
            #pragma unroll
            for (int c = 0; c < AC; ++c)
                av[c] = *(const float4*)(A + (size_t)(m0 + c*16 + am_row)*HH + k0 + am_col);
            short8v bv[4];
            #pragma unroll
            for (int i = 0; i < 4; ++i)
                bv[i] = *(const short8v*)(WT + (size_t)(n0 + i*32 + bm_row)*HH + k0 + bm_col);
            __syncthreads();
            #pragma unroll
            for (int c = 0; c < AC; ++c) {
                int r = c*16 + am_row;
                short4v h;
                h[0]=(short)f2bf(av[c].x); h[1]=(short)f2bf(av[c].y);
                h[2]=(short)f2bf(av[c].z); h[3]=(short)f2bf(av[c].w);
                int ba = r*128 + ((am_col*2) ^ ((r & 7) << 4));
                *(short4v*)&As[ba >> 1] = h;
            }
            #pragma unroll
            for (int i = 0; i < 4; ++i) {
                int r = i*32 + bm_row;
                int ba = r*128 + ((bm_col*2) ^ ((r & 7) << 4));
                *(short8v*)&Bs[ba >> 1] = bv[i];
            }
            __syncthreads();
            #pragma unroll
            for (int ks = 0; ks < 2; ++ks) {
                const int kb = ks*64 + l4*16;
                short8v af[FM], bf[4];
                #pragma unroll
                for (int fm = 0; fm < FM; ++fm) {
                    int row = wm*(FM*16) + fm*16 + l15;
                    af[fm] = *(const short8v*)&As[(row*128 + (kb ^ ((row & 7) << 4))) >> 1];
                }
                #pragma unroll
                for (int fn = 0; fn < 4; ++fn) {
                    int row = wn*64 + fn*16 + l15;
                    bf[fn] = *(const short8v*)&Bs[(row*128 + (kb ^ ((row & 7) << 4))) >> 1];
                }
                #pragma unroll
                for (int fm = 0; fm < FM; ++fm)
                    #pragma unroll
                    for (int fn = 0; fn < 4; ++fn)
                        acc[fm][fn] = __builtin_amdgcn_mfma_f32_16x16x32_bf16(af[fm], bf[fn], acc[fm][fn], 0, 0, 0);
            }
            __syncthreads();
        }
    }
    #pragma unroll
    for (int fn = 0; fn < 4; ++fn) {
        int col = n0 + wn*64 + fn*16 + l15;
        float bb = bias ? bias[col] : 0.f;
        #pragma unroll
        for (int fm = 0; fm < FM; ++fm) {
            int row0 = m0 + wm*(FM*16) + fm*16 + l4*4;
            #pragma unroll
            for (int j = 0; j < 4; ++j) {
                float v = acc[fm][fn][j] + bb;
                if (act) v = gelu_erf(v);
                C[(size_t)(row0 + j)*HH + col] = v;
            }
        }
    }
}

// ---------------------------------------------------------------- fused MFMA message GEMM v7
// m97 structure: 128x128 tile, BK=64, both operands via global_load_lds (16B)
// into LINEAR LDS (2-phase regime: swizzle is null per m228d/m230), 2 barriers
// per K-step, no f32->bf16 in the hot loop (rel pre-converted by k_cvt).
// Epilogue (proven in r8 k_msg5): gather tail + dk, gelu, weighted r-reduce.
__global__ __launch_bounds__(256, 3) void k_msg7(
    const unsigned short* __restrict__ relbf, const unsigned short* __restrict__ CkT,
    const float* __restrict__ dk, const float* __restrict__ eeW,
    const float* __restrict__ weight, const int* __restrict__ adj,
    float* __restrict__ agg)
{
    __shared__ alignas(16) unsigned short As[128*64];    // 16KB linear [row][64]
    __shared__ alignas(16) unsigned short Bs[128*64];    // 16KB linear [nrow][64]
    __shared__ int   adjS[4][RR];
    __shared__ float wS[4][RR];
    const int tid = threadIdx.x;
    // bijective XCD swizzle: 3072 = 8 * 384, n-fastest logical order
    const int bid = blockIdx.x;
    const int L = (bid & 7) * 384 + (bid >> 3);
    const int mt = L / 6, nt = L - mt*6;
    const int n0 = nt * 128;
    const int m0 = mt * 128;
    const int be0 = mt * 4;              // 4 entities per block
    const int b = be0 >> 9;
    if (tid < 128) {
        int el = tid >> 5, r = tid & 31;
        adjS[el][r] = adj[(be0 + el)*RR + r];
        wS[el][r]   = weight[(be0 + el)*RR + r];
    }
    const int w = tid >> 6, lane = tid & 63;
    const int wm = w >> 1, wn = w & 1;
    const int l15 = lane & 15, l4 = lane >> 4;
    // gload_lds source geometry: chunk = 8 rows x 128B = 1KB; lane l covers
    // row crow = l>>3 of the chunk, bytes (l&7)*16 of that row's K-slice.
    const int crow = lane >> 3;
    const int ce   = (lane & 7) * 8;     // ushort offset within row K-slice

    f32x4 acc[4][4];
    #pragma unroll
    for (int i = 0; i < 4; ++i)
        #pragma unroll
        for (int j = 0; j < 4; ++j) acc[i][j] = (f32x4){0.f,0.f,0.f,0.f};

    for (int t = 0; t < 12; ++t) {
        const int k0 = t*64;
        // stage: wave w issues 4 A-chunks + 4 B-chunks (rows w*32..w*32+31)
        #pragma unroll
        for (int c = 0; c < 4; ++c) {
            int rbase = w*32 + c*8;
            GLOAD_LDS16(relbf + (size_t)(m0 + rbase + crow)*HH + k0 + ce,
                        &As[rbase*64]);
            GLOAD_LDS16(CkT   + (size_t)(n0 + rbase + crow)*HH + k0 + ce,
                        &Bs[rbase*64]);
        }
        __syncthreads();    // compiler drains vmcnt before the barrier
        // compute: 2 K-slices x 16 MFMA per wave
        #pragma unroll
        for (int ks = 0; ks < 2; ++ks) {
            const int ko = ks*32 + l4*8;     // ushort offset in row
            short8v af[4], bf[4];
            #pragma unroll
            for (int fm = 0; fm < 4; ++fm) {
                int row = wm*64 + fm*16 + l15;
                af[fm] = *(const short8v*)&As[row*64 + ko];
            }
            #pragma unroll
            for (int fn = 0; fn < 4; ++fn) {
                int row = wn*64 + fn*16 + l15;
                bf[fn] = *(const short8v*)&Bs[row*64 + ko];
            }
            #pragma unroll
            for (int fm = 0; fm < 4; ++fm)
                #pragma unroll
                for (int fn = 0; fn < 4; ++fn)
                    acc[fm][fn] = __builtin_amdgcn_mfma_f32_16x16x32_bf16(af[fm], bf[fn], acc[fm][fn], 0, 0, 0);
        }
        __syncthreads();
    }

    // epilogue: gather tail + dk, gelu, weight, reduce over r (r8-proven)
    #pragma unroll
    for (int eh = 0; eh < 2; ++eh) {
        const int el = wm*2 + eh;
        const int be = be0 + el;
        #pragma unroll
        for (int fn = 0; fn < 4; ++fn) {
            int col = n0 + wn*64 + fn*16 + l15;
            float d = dk[col];
            float s = 0.f;
            #pragma unroll
            for (int fp = 0; fp < 2; ++fp) {
                const int fm = eh*2 + fp;
                #pragma unroll
                for (int j = 0; j < 4; ++j) {
                    int rr = fp*16 + l4*4 + j;
                    int tl = adjS[el][rr];
                    float tail = eeW[((size_t)(b*EE_N + tl))*HH + col];
                    s += wS[el][rr] * gelu_erf(acc[fm][fn][j] + tail + d);
                }
            }
            s += __shfl_xor(s, 16);
            s += __shfl_xor(s, 32);
            if (l4 == 0) agg[(size_t)be*HH + col] = s;
        }
    }
}

// ---------------------------------------------------------------- fused MFMA message GEMM v6 (fallback, r9-proven)
template<int FUSE>
__global__ __launch_bounds__(256, 3) void k_msg6(
    const float* __restrict__ rel, const unsigned short* __restrict__ CkT,
    const float* __restrict__ dk, const float* __restrict__ eeW,
    const float* __restrict__ weight_in, const int* __restrict__ adj,
    const float* __restrict__ wr1c, const float* __restrict__ qd,
    const float* __restrict__ am,
    float* __restrict__ agg, float* __restrict__ logit_out,
    float* __restrict__ weight_out)
{
    __shared__ alignas(16) unsigned short As[64*64];
    __shared__ alignas(16) unsigned short Bs[256*64];
    int*   adjS = (int*)As;
    float* wS   = (float*)(As + 128);
    float* lgS  = (float*)(As + 256);
    const int tid = threadIdx.x;
    const int bid = blockIdx.x;
    const int L = (bid & 7) * 384 + (bid >> 3);
    const int mt = L / 3, nt = L - mt*3;
    const int n0 = nt * 256;
    const int m0 = mt * 64;
    const int be0 = mt * 2;
    const int b = be0 >> 9;
    const int wn = tid >> 6, lane = tid & 63;
    const int l15 = lane & 15, l4 = lane >> 4;
    const int am_row = tid >> 4;
    const int am_col = (tid & 15) * 4;
    const int bm_row = tid >> 3;
    const int bm_col = (tid & 7) * 8;
    const float* apA = rel + (size_t)(m0 + am_row)*HH + am_col;
    const unsigned short* apB = CkT + (size_t)(n0 + bm_row)*HH + bm_col;
    f32x4 acc[4][4];
    #pragma unroll
    for (int i = 0; i < 4; ++i)
        #pragma unroll
        for (int j = 0; j < 4; ++j) acc[i][j] = (f32x4){0.f,0.f,0.f,0.f};
    float lg[4] = {0.f, 0.f, 0.f, 0.f};
    float4 av[4];
    short8v bv[8];
    #pragma unroll
    for (int c = 0; c < 4; ++c) av[c] = *(const float4*)(apA + (size_t)c*16*HH);
    #pragma unroll
    for (int i = 0; i < 8; ++i) bv[i] = *(const short8v*)(apB + (size_t)i*32*HH);
    for (int t = 0; t < 12; ++t) {
        const int k0 = t*64;
        #pragma unroll
        for (int c = 0; c < 4; ++c) {
            int r = c*16 + am_row;
            short4v h;
            h[0]=(short)f2bf(av[c].x); h[1]=(short)f2bf(av[c].y);
            h[2]=(short)f2bf(av[c].z); h[3]=(short)f2bf(av[c].w);
            int ba = r*128 + ((am_col*2) ^ ((r & 7) << 4));
            *(short4v*)&As[ba >> 1] = h;
        }
        #pragma unroll
        for (int i = 0; i < 8; ++i) {
            int r = i*32 + bm_row;
            int ba = r*128 + ((bm_col*2) ^ ((r & 7) << 4));
            *(short8v*)&Bs[ba >> 1] = bv[i];
        }
        if (FUSE) {
            float4 wv = *(const float4*)(wr1c + k0 + am_col);
            #pragma unroll
            for (int c = 0; c < 4; ++c)
                lg[c] += av[c].x*wv.x + av[c].y*wv.y + av[c].z*wv.z + av[c].w*wv.w;
        }
        if (t < 11) {
            #pragma unroll
            for (int c = 0; c < 4; ++c)
                av[c] = *(const float4*)(apA + (size_t)c*16*HH + k0 + 64);
            #pragma unroll
            for (int i = 0; i < 8; ++i)
                bv[i] = *(const short8v*)(apB + (size_t)i*32*HH + k0 + 64);
        }
        __syncthreads();
        #pragma unroll
        for (int ks = 0; ks < 2; ++ks) {
            const int kb = ks*64 + l4*16;
            short8v af[4], bf[4];
            #pragma unroll
            for (int fm = 0; fm < 4; ++fm) {
                int row = fm*16 + l15;
                af[fm] = *(const short8v*)&As[(row*128 + (kb ^ ((row & 7) << 4))) >> 1];
            }
            #pragma unroll
            for (int fn = 0; fn < 4; ++fn) {
                int row = wn*64 + fn*16 + l15;
                bf[fn] = *(const short8v*)&Bs[(row*128 + (kb ^ ((row & 7) << 4))) >> 1];
            }
            #pragma unroll
            for (int fm = 0; fm < 4; ++fm)
                #pragma unroll
                for (int fn = 0; fn < 4; ++fn)
                    acc[fm][fn] = __builtin_amdgcn_mfma_f32_16x16x32_bf16(af[fm], bf[fn], acc[fm][fn], 0, 0, 0);
        }
        __syncthreads();
    }
    if (tid < 64) adjS[tid] = adj[be0*RR + tid];
    if (!FUSE && tid < 64) wS[tid] = weight_in[be0*RR + tid];
    if (FUSE) {
        #pragma unroll
        for (int c = 0; c < 4; ++c) {
            lg[c] += __shfl_xor(lg[c], 1);
            lg[c] += __shfl_xor(lg[c], 2);
            lg[c] += __shfl_xor(lg[c], 4);
            lg[c] += __shfl_xor(lg[c], 8);
        }
        if ((tid & 15) == 0) {
            #pragma unroll
            for (int c = 0; c < 4; ++c) lgS[c*16 + am_row] = lg[c];
        }
        __syncthreads();
        if (tid < 64) {
            float amv = am[be0*RR + tid];
            float l = lgS[tid] + qd[b] + qd[BB] + (1.0f - amv) * NEGF;
            float mx = l;
            #pragma unroll
            for (int off = 16; off; off >>= 1) mx = fmaxf(mx, __shfl_xor(mx, off, 32));
            float e = expf(l - mx);
            float sm = e;
            #pragma unroll
            for (int off = 16; off; off >>= 1) sm += __shfl_xor(sm, off, 32);
            float wgt = amv * e / sm;
            wS[tid] = wgt;
            if (nt == 0) {
                logit_out[be0*RR + tid] = l;
                weight_out[be0*RR + tid] = wgt;
            }
        }
    }
    __syncthreads();
    #pragma unroll
    for (int eh = 0; eh < 2; ++eh) {
        const int be = be0 + eh;
        #pragma unroll
        for (int fn = 0; fn < 4; ++fn) {
            int col = n0 + wn*64 + fn*16 + l15;
            float d = dk[col];
            float s = 0.f;
            #pragma unroll
            for (int fp = 0; fp < 2; ++fp) {
                const int fm = eh*2 + fp;
                #pragma unroll
                for (int j = 0; j < 4; ++j) {
                    int rr = fp*16 + l4*4 + j;
                    int tl = adjS[eh*RR + rr];
                    float tail = eeW[((size_t)(b*EE_N + tl))*HH + col];
                    s += wS[eh*RR + rr] * gelu_erf(acc[fm][fn][j] + tail + d);
                }
            }
            s += __shfl_xor(s, 16);
            s += __shfl_xor(s, 32);
            if (l4 == 0) agg[(size_t)be*HH + col] = s;
        }
    }
}

// ---------------------------------------------------------------- ent_score + sdot
__global__ __launch_bounds__(256) void k_score(const float* __restrict__ ee,
                                               const float* __restrict__ SW,
                                               const float* __restrict__ SB,
                                               const float* __restrict__ NM,
                                               const float* __restrict__ q,
                                               float* __restrict__ score,
                                               float* __restrict__ sdot) {
    const int wid = threadIdx.x >> 6, lane = threadIdx.x & 63;
    const int row = blockIdx.x*4 + wid;
    const int b = row >> 9;
    const float* er = ee + (size_t)row*HH;
    const float* qr = q + b*HH;
    float a1 = 0.f, a2 = 0.f;
    #pragma unroll
    for (int p = 0; p < 3; ++p) {
        int i4 = (p*64 + lane) << 2;
        float4 e4 = *(const float4*)(er + i4);
        float4 s4 = *(const float4*)(SW + i4);
        float4 q4 = *(const float4*)(qr + i4);
        a1 += e4.x*s4.x + e4.y*s4.y + e4.z*s4.z + e4.w*s4.w;
        a2 += e4.x*q4.x + e4.y*q4.y + e4.z*q4.z + e4.w*q4.w;
    }
    for (int off = 32; off; off >>= 1) { a1 += __shfl_xor(a1, off); a2 += __shfl_xor(a2, off); }
    if (lane == 0) {
        score[row] = a1 + SB[0] + (1.0f - NM[row]) * NEGF;
        sdot[row] = a2;
    }
}

// ---------------------------------------------------------------- triple_sim
__global__ void k_triple(const float* __restrict__ sdot, const int* __restrict__ adj,
                         const float* __restrict__ logit, float* __restrict__ tri) {
    int idx = blockIdx.x*256 + threadIdx.x;
    int b = idx >> 14;
    int n = idx & 16383;
    int e = n >> 5;
    int a = adj[idx];
    tri[idx] = sdot[b*EE_N + e] + sdot[b*EE_N + a] + logit[idx];
}

// ================================================================ launch
extern "C" void kernel_launch(void* const* d_in, const int* in_sizes, int n_in,
                              void* d_out, int out_size, void* d_ws, size_t ws_size,
                              hipStream_t stream) {
    const float* QE  = (const float*)d_in[0];
    const float* QM  = (const float*)d_in[1];
    const float* ENT = (const float*)d_in[2];
    const float* REL = (const float*)d_in[3];
    const int*   ADJ = (const int*)d_in[4];
    const float* NM  = (const float*)d_in[5];
    const float* AM  = (const float*)d_in[6];
    const float* PW  = (const float*)d_in[7];
    const float* PB  = (const float*)d_in[8];
    const float* RW  = (const float*)d_in[9];
    const float* RB  = (const float*)d_in[10];
    const float* MW  = (const float*)d_in[11];
    const float* MB  = (const float*)d_in[12];
    const float* UW  = (const float*)d_in[13];
    const float* UB  = (const float*)d_in[14];
    const float* RSW = (const float*)d_in[15];
    const float* RSB = (const float*)d_in[16];
    const float* SW  = (const float*)d_in[17];
    const float* SB  = (const float*)d_in[18];

    float* out = (float*)d_out;
    float* ws  = (float*)d_ws;
    float* o_ee    = out;                       // [4,512,768]
    float* o_score = out + 1572864;             // [4,512]
    float* o_logit = out + 1574912;             // [4,512,32]
    float* o_tri   = out + 1640448;             // [4,16384]

    unsigned short* CkT0 = (unsigned short*)(ws + WS_CKT0);
    unsigned short* CkT1 = (unsigned short*)(ws + WS_CKT1);
    unsigned short* PWT  = (unsigned short*)(ws + WS_PWT);
    unsigned short* W0bT = (unsigned short*)(ws + WS_W0BT);
    unsigned short* W1bT = (unsigned short*)(ws + WS_W1BT);
    unsigned short* U0tT = (unsigned short*)(ws + WS_U0TT);
    unsigned short* U0bT = (unsigned short*)(ws + WS_U0BT);
    unsigned short* U1tT = (unsigned short*)(ws + WS_U1TT);
    unsigned short* U1bT = (unsigned short*)(ws + WS_U1BT);
    unsigned short* M0tT = (unsigned short*)(ws + WS_M0TT);
    unsigned short* M1tT = (unsigned short*)(ws + WS_M1TT);
    unsigned short* RELBF = (unsigned short*)(ws + WS_RELBF);

    const bool big = ws_size >= WS_NEED_BYTES;   // deterministic path choice

    const size_t HT = (size_t)2*HH*HH;          // per-hop stride in msg_W/upd_W
    const size_t BOT = (size_t)HH*HH;           // bottom-half offset

    // q path + small vectors
    k_qbar<<<BB, 256, 0, stream>>>(QE, QM, ws + WS_QBAR);
    gemm_f32<<<dim3(12,1), 256, 0, stream>>>(ws + WS_QBAR, PW, PB, ws + WS_Q, BB, HH, HH, 0);
    k_small2<<<193, 256, 0, stream>>>(RW, RB, RSW, RSB, ws + WS_Q, ws + WS_WR1C, ws + WS_QD);

    // batch-transpose the 9 static weights to bf16 [n][k]
    WPairs wp;
    wp.s[0] = PW;            wp.d[0] = PWT;
    wp.s[1] = MW + BOT;      wp.d[1] = W0bT;
    wp.s[2] = MW + HT + BOT; wp.d[2] = W1bT;
    wp.s[3] = UW;            wp.d[3] = U0tT;
    wp.s[4] = UW + BOT;      wp.d[4] = U0bT;
    wp.s[5] = UW + HT;       wp.d[5] = U1tT;
    wp.s[6] = UW + HT + BOT; wp.d[6] = U1bT;
    wp.s[7] = MW;            wp.d[7] = M0tT;
    wp.s[8] = MW + HT;       wp.d[8] = M1tT;
    k_w2bf<<<dim3(24,24,9), 256, 0, stream>>>(wp);

    // dk vectors from the transposed bf16 top-half message weights
    k_dk2<<<384, 256, 0, stream>>>(M0tT, M1tT, RB, MB, ws + WS_D0, ws + WS_D1);

    // composite message weights  C_k = rproj_W @ msg_W[k][:768,:]  (MFMA) -> CkT bf16
    gemm_bf16<32><<<dim3(6,24), 256, 0, stream>>>(RW, M0tT, nullptr, nullptr, nullptr,
                                                  ws + WS_C0, 0);
    gemm_bf16<32><<<dim3(6,24), 256, 0, stream>>>(RW, M1tT, nullptr, nullptr, nullptr,
                                                  ws + WS_C1, 0);
    k_ckt<<<dim3(24,24), 256, 0, stream>>>(ws + WS_C0, CkT0);
    k_ckt<<<dim3(24,24), 256, 0, stream>>>(ws + WS_C1, CkT1);

    // ee0 = entity_embedding @ proj_W + proj_b   (bf16 MFMA)
    gemm_bf16<32><<<dim3(6,64), 256, 0, stream>>>(ENT, PWT, nullptr, nullptr, PB,
                                                  ws + WS_EEA, 0);

    if (big) {
        // rel -> bf16 (+ fused logit), then softmax weights
        k_cvt<<<16384, 256, 0, stream>>>(REL, ws + WS_WR1C, ws + WS_QD, AM,
                                         RELBF, o_logit);
        k_softmax<<<2048, 64, 0, stream>>>(o_logit, AM, ws + WS_W);

        // hop 0
        gemm_bf16<32><<<dim3(6,64), 256, 0, stream>>>(ws + WS_EEA, W0bT, nullptr, nullptr, nullptr,
                                                      ws + WS_EEW, 0);
        k_msg7<<<3072, 256, 0, stream>>>(RELBF, CkT0, ws + WS_D0, ws + WS_EEW,
                                         ws + WS_W, ADJ, ws + WS_AGG);
        gemm_bf16<32><<<dim3(6,64), 256, 0, stream>>>(ws + WS_EEA, U0tT, ws + WS_AGG, U0bT, UB,
                                                      ws + WS_EEB, 1);
        // hop 1
        gemm_bf16<32><<<dim3(6,64), 256, 0, stream>>>(ws + WS_EEB, W1bT, nullptr, nullptr, nullptr,
                                                      ws + WS_EEW, 0);
        k_msg7<<<3072, 256, 0, stream>>>(RELBF, CkT1, ws + WS_D1, ws + WS_EEW,
                                         ws + WS_W, ADJ, ws + WS_AGG);
        gemm_bf16<32><<<dim3(6,64), 256, 0, stream>>>(ws + WS_EEB, U1tT, ws + WS_AGG, U1bT,
                                                      UB + HH, o_ee, 1);
    } else {
        // fallback: round-9 proven path (reg-staged k_msg6, fused logit)
        gemm_bf16<32><<<dim3(6,64), 256, 0, stream>>>(ws + WS_EEA, W0bT, nullptr, nullptr, nullptr,
                                                      ws + WS_EEW, 0);
        k_msg6<1><<<3072, 256, 0, stream>>>(REL, CkT0, ws + WS_D0, ws + WS_EEW,
                                            nullptr, ADJ, ws + WS_WR1C, ws + WS_QD, AM,
                                            ws + WS_AGG, o_logit, ws + WS_W);
        gemm_bf16<32><<<dim3(6,64), 256, 0, stream>>>(ws + WS_EEA, U0tT, ws + WS_AGG, U0bT, UB,
                                                      ws + WS_EEB, 1);
        gemm_bf16<32><<<dim3(6,64), 256, 0, stream>>>(ws + WS_EEB, W1bT, nullptr, nullptr, nullptr,
                                                      ws + WS_EEW, 0);
        k_msg6<0><<<3072, 256, 0, stream>>>(REL, CkT1, ws + WS_D1, ws + WS_EEW,
                                            ws + WS_W, ADJ, ws + WS_WR1C, ws + WS_QD, AM,
                                            ws + WS_AGG, nullptr, nullptr);
        gemm_bf16<32><<<dim3(6,64), 256, 0, stream>>>(ws + WS_EEB, U1tT, ws + WS_AGG, U1bT,
                                                      UB + HH, o_ee, 1);
    }

    // scores + triple_sim
    k_score<<<512, 256, 0, stream>>>(o_ee, SW, SB, NM, ws + WS_Q, o_score, ws + WS_SDOT);
    k_triple<<<256, 256, 0, stream>>>(ws + WS_SDOT, ADJ, o_logit, o_tri);
}

// Round 11
// 502.079 us; speedup vs baseline: 1.1661x; 1.1661x over previous
//
#include <hip/hip_runtime.h>

// NOTE: reference uses finfo(f32).min = -3.4028e38, which rounds to -inf in
// bf16 — the harness compares through bf16, and (-inf) - (-inf) = nan fails.
// -3.0e38 is finite in bf16, semantically identical through softmax/masking.
#define NEGF (-3.0e38f)

// problem sizes
#define BB 4
#define LQQ 64
#define EE_N 512
#define RR 32
#define HH 768

// workspace offsets (floats)
#define WS_QBAR 0
#define WS_Q    3072
#define WS_QD   6144
#define WS_WR1C 6656
#define WS_D0   7424
#define WS_D1   8192
#define WS_C0   8960
#define WS_C1   598784
#define WS_EEA  1188608
#define WS_EEB  2761472
#define WS_EEW  4334336
#define WS_W    5907200
#define WS_AGG  5972736
#define WS_SDOT 7545600
#define WS_CKT0 7547648
#define WS_CKT1 7842560
#define WS_PWT  8137472
#define WS_W0BT 8432384
#define WS_W1BT 8727296
#define WS_U0TT 9022208
#define WS_U0BT 9317120
#define WS_U1TT 9612032
#define WS_U1BT 9906944
#define WS_M0TT 10201856
#define WS_M1TT 10496768
#define WS_RELBF 10791680
// big path total: 10791680 + 25165824 = 35957504 floats = 143.8 MB
#define WS_NEED_BYTES 143830016ull

typedef __attribute__((ext_vector_type(8))) short short8v;
typedef __attribute__((ext_vector_type(4))) short short4v;
typedef __attribute__((ext_vector_type(4))) float f32x4;

#define GLOAD_LDS16(gp, lp) __builtin_amdgcn_global_load_lds( \
    (const __attribute__((address_space(1))) void*)(gp), \
    (__attribute__((address_space(3))) void*)(lp), 16, 0, 0)

__device__ __forceinline__ float gelu_erf(float x) {
    return 0.5f * x * (1.0f + erff(x * 0.70710678118654752f));
}

__device__ __forceinline__ unsigned short f2bf(float f) {
    unsigned int u = __float_as_uint(f);
    unsigned int r = (u + 0x7fffu + ((u >> 16) & 1u)) >> 16;   // RNE
    return (unsigned short)r;
}

__device__ __forceinline__ float bf2f(unsigned short h) {
    return __uint_as_float(((unsigned int)h) << 16);
}

// ---------------------------------------------------------------- qbar
__global__ void k_qbar(const float* __restrict__ QE, const float* __restrict__ QM,
                       float* __restrict__ qbar) {
    int b = blockIdx.x;
    int tid = threadIdx.x;
    float msum = 0.f;
    for (int l = 0; l < LQQ; ++l) msum += QM[b*LQQ + l];
    for (int h = tid; h < HH; h += 256) {
        float s = 0.f;
        for (int l = 0; l < LQQ; ++l)
            s += QM[b*LQQ + l] * QE[((size_t)(b*LQQ + l))*HH + h];
        qbar[b*HH + h] = s / msum;
    }
}

// ---------------------------------------------------------------- small vectors (wave-parallel)
__global__ void k_small2(const float* __restrict__ RW, const float* __restrict__ RB,
                         const float* __restrict__ RSW, const float* __restrict__ RSB,
                         const float* __restrict__ q, float* __restrict__ wr1c,
                         float* __restrict__ qd) {
    const int wid = threadIdx.x >> 6, lane = threadIdx.x & 63;
    const int blk = blockIdx.x;
    if (blk < 192) {
        int row = blk*4 + wid;
        const float* a = RW + (size_t)row*HH;
        float acc = 0.f;
        #pragma unroll
        for (int p = 0; p < 3; ++p) {
            int i4 = (p*64 + lane) << 2;
            float4 x = *(const float4*)(a + i4);
            float4 w = *(const float4*)(RSW + i4);
            acc += x.x*w.x + x.y*w.y + x.z*w.z + x.w*w.w;
        }
        for (int off = 32; off; off >>= 1) acc += __shfl_xor(acc, off);
        if (lane == 0) wr1c[row] = acc;
    } else {
        float acc = 0.f, acc2 = 0.f;
        const float* src = q + wid*HH;
        #pragma unroll
        for (int p = 0; p < 3; ++p) {
            int i4 = (p*64 + lane) << 2;
            float4 x = *(const float4*)(src + i4);
            float4 w = *(const float4*)(RSW + HH + i4);
            acc += x.x*w.x + x.y*w.y + x.z*w.z + x.w*w.w;
            if (wid == 0) {
                float4 rb = *(const float4*)(RB + i4);
                float4 w0 = *(const float4*)(RSW + i4);
                acc2 += rb.x*w0.x + rb.y*w0.y + rb.z*w0.z + rb.w*w0.w;
            }
        }
        for (int off = 32; off; off >>= 1) { acc += __shfl_xor(acc, off); acc2 += __shfl_xor(acc2, off); }
        if (lane == 0) qd[wid] = acc;
        if (wid == 0 && lane == 0) qd[BB] = acc2 + RSB[0];
    }
}

// ---------------------------------------------------------------- dk via transposed bf16 weights
__global__ void k_dk2(const unsigned short* __restrict__ M0tT,
                      const unsigned short* __restrict__ M1tT,
                      const float* __restrict__ RB, const float* __restrict__ MB,
                      float* __restrict__ d0, float* __restrict__ d1) {
    const int gw = blockIdx.x*4 + (threadIdx.x >> 6);   // 0..1535
    const int lane = threadIdx.x & 63;
    const int hop = gw >= HH;
    const int n = hop ? gw - HH : gw;
    const unsigned short* row = (hop ? M1tT : M0tT) + (size_t)n*HH;
    float s = 0.f;
    #pragma unroll
    for (int p = 0; p < 3; ++p) {
        int i4 = (p*64 + lane) << 2;
        const unsigned short* hp = row + i4;
        float4 rv = *(const float4*)(RB + i4);
        s += bf2f(hp[0])*rv.x + bf2f(hp[1])*rv.y + bf2f(hp[2])*rv.z + bf2f(hp[3])*rv.w;
    }
    for (int off = 32; off; off >>= 1) s += __shfl_xor(s, off);
    if (lane == 0) (hop ? d1 : d0)[n] = s + MB[hop*HH + n];
}

// ---------------------------------------------------------------- generic GEMM f32 (tiny M only)
__global__ __launch_bounds__(256) void gemm_f32(
    const float* __restrict__ A1, const float* __restrict__ W1,
    const float* __restrict__ bias, float* __restrict__ C,
    int M, int N, int K, int act)
{
    __shared__ float Asm[16][68];
    __shared__ float Bs[16][68];
    const int tid = threadIdx.x;
    const int n0 = blockIdx.x * 64;
    const int m0 = blockIdx.y * 64;
    const int tm = tid >> 4;
    const int tn = tid & 15;
    float acc[4][4] = {};
    for (int kk = 0; kk < K; kk += 16) {
        const int ar = tid >> 2;
        const int ak = (tid & 3) << 2;
        float4 av = make_float4(0.f, 0.f, 0.f, 0.f);
        if (m0 + ar < M) av = *(const float4*)(A1 + (size_t)(m0 + ar)*K + kk + ak);
        const int br = tid >> 4;
        const int bc = (tid & 15) << 2;
        float4 bv = *(const float4*)(W1 + (size_t)(kk + br)*N + n0 + bc);
        __syncthreads();
        Asm[ak+0][ar] = av.x; Asm[ak+1][ar] = av.y;
        Asm[ak+2][ar] = av.z; Asm[ak+3][ar] = av.w;
        *(float4*)&Bs[br][bc] = bv;
        __syncthreads();
        #pragma unroll
        for (int k = 0; k < 16; ++k) {
            float4 a4 = *(const float4*)&Asm[k][tm << 2];
            float4 b4 = *(const float4*)&Bs[k][tn << 2];
            float a[4] = {a4.x, a4.y, a4.z, a4.w};
            float b[4] = {b4.x, b4.y, b4.z, b4.w};
            #pragma unroll
            for (int i = 0; i < 4; ++i)
                #pragma unroll
                for (int j = 0; j < 4; ++j)
                    acc[i][j] = fmaf(a[i], b[j], acc[i][j]);
        }
    }
    float4 bb = make_float4(0.f, 0.f, 0.f, 0.f);
    if (bias) bb = *(const float4*)(bias + n0 + (tn << 2));
    float bbv[4] = {bb.x, bb.y, bb.z, bb.w};
    #pragma unroll
    for (int i = 0; i < 4; ++i) {
        int m = m0 + (tm << 2) + i;
        if (m >= M) break;
        #pragma unroll
        for (int j = 0; j < 4; ++j) {
            float v = acc[i][j] + bbv[j];
            if (act) v = gelu_erf(v);
            C[(size_t)m*N + n0 + (tn << 2) + j] = v;
        }
    }
}

// ---------------------------------------------------------------- f32 [K][N] -> bf16 [N][K]
__global__ void k_ckt(const float* __restrict__ Ck, unsigned short* __restrict__ CkT) {
    __shared__ float t[32][33];
    const int k0 = blockIdx.x * 32, n0 = blockIdx.y * 32;
    const int tid = threadIdx.x;   // 256
    {
        int r = tid >> 3;
        int c4 = (tid & 7) << 2;
        float4 v = *(const float4*)(Ck + (size_t)(k0 + r)*HH + n0 + c4);
        t[r][c4+0] = v.x; t[r][c4+1] = v.y; t[r][c4+2] = v.z; t[r][c4+3] = v.w;
    }
    __syncthreads();
    {
        int n = tid >> 3;
        int k4 = (tid & 7) << 2;
        unsigned short o[4];
        #pragma unroll
        for (int j = 0; j < 4; ++j) o[j] = f2bf(t[k4+j][n]);
        *(uint2*)(CkT + (size_t)(n0 + n)*HH + k0 + k4) = *(const uint2*)o;
    }
}

// batched version for the 9 input weight matrices
struct WPairs { const float* s[9]; unsigned short* d[9]; };
__global__ void k_w2bf(WPairs p) {
    __shared__ float t[32][33];
    const float* __restrict__ Ck = p.s[blockIdx.z];
    unsigned short* __restrict__ CkT = p.d[blockIdx.z];
    const int k0 = blockIdx.x * 32, n0 = blockIdx.y * 32;
    const int tid = threadIdx.x;
    {
        int r = tid >> 3;
        int c4 = (tid & 7) << 2;
        float4 v = *(const float4*)(Ck + (size_t)(k0 + r)*HH + n0 + c4);
        t[r][c4+0] = v.x; t[r][c4+1] = v.y; t[r][c4+2] = v.z; t[r][c4+3] = v.w;
    }
    __syncthreads();
    {
        int n = tid >> 3;
        int k4 = (tid & 7) << 2;
        unsigned short o[4];
        #pragma unroll
        for (int j = 0; j < 4; ++j) o[j] = f2bf(t[k4+j][n]);
        *(uint2*)(CkT + (size_t)(n0 + n)*HH + k0 + k4) = *(const uint2*)o;
    }
}

// ---------------------------------------------------------------- rel f32 -> bf16 + fused logit
__global__ __launch_bounds__(256) void k_cvt(
    const float* __restrict__ rel, const float* __restrict__ wr1c,
    const float* __restrict__ qd, const float* __restrict__ am,
    unsigned short* __restrict__ relbf, float* __restrict__ logit) {
    const int wid = threadIdx.x >> 6, lane = threadIdx.x & 63;
    const long row = (long)blockIdx.x*4 + wid;   // < 65536
    const float* a = rel + row*HH;
    unsigned short* o = relbf + row*HH;
    float acc = 0.f;
    #pragma unroll
    for (int p = 0; p < 3; ++p) {
        int i4 = (p*64 + lane) << 2;
        float4 x = *(const float4*)(a + i4);
        float4 wv = *(const float4*)(wr1c + i4);
        acc += x.x*wv.x + x.y*wv.y + x.z*wv.z + x.w*wv.w;
        unsigned short h[4] = {f2bf(x.x), f2bf(x.y), f2bf(x.z), f2bf(x.w)};
        *(uint2*)(o + i4) = *(const uint2*)h;
    }
    for (int off = 32; off; off >>= 1) acc += __shfl_xor(acc, off);
    if (lane == 0) {
        int b = (int)(row >> 14);
        logit[row] = acc + qd[b] + qd[BB] + (1.0f - am[row]) * NEGF;
    }
}

// ---------------------------------------------------------------- softmax over R=32
__global__ void k_softmax(const float* __restrict__ logit, const float* __restrict__ am,
                          float* __restrict__ weight) {
    int row = blockIdx.x;
    int lane = threadIdx.x;
    if (lane < 32) {
        float l = logit[row*RR + lane];
        float m = l;
        for (int off = 16; off; off >>= 1) m = fmaxf(m, __shfl_xor(m, off, 32));
        float e = expf(l - m);
        float s = e;
        for (int off = 16; off; off >>= 1) s += __shfl_xor(s, off, 32);
        weight[row*RR + lane] = am[row*RR + lane] * e / s;
    }
}

// ---------------------------------------------------------------- tiled bf16 MFMA GEMM
template<int BM>
__global__ __launch_bounds__(256) void gemm_bf16(
    const float* __restrict__ A1, const unsigned short* __restrict__ W1T,
    const float* __restrict__ A2, const unsigned short* __restrict__ W2T,
    const float* __restrict__ bias, float* __restrict__ C, int act)
{
    constexpr int FM = BM / 32;             // m-frags per wave (min 1)
    constexpr int AC = BM / 16;             // A 16-row chunks
    __shared__ alignas(16) unsigned short As[BM*64];
    __shared__ alignas(16) unsigned short Bs[128*64];
    const int tid = threadIdx.x;
    const int n0 = blockIdx.x * 128;
    const int m0 = blockIdx.y * BM;
    const int w = tid >> 6, lane = tid & 63;
    const int wm = w >> 1, wn = w & 1;
    const int l15 = lane & 15, l4 = lane >> 4;
    const int am_row = tid >> 4;
    const int am_col = (tid & 15) * 4;
    const int bm_row = tid >> 3;
    const int bm_col = (tid & 7) * 8;
    f32x4 acc[FM][4];
    #pragma unroll
    for (int i = 0; i < FM; ++i)
        #pragma unroll
        for (int j = 0; j < 4; ++j) acc[i][j] = (f32x4){0.f,0.f,0.f,0.f};
    const int nPass = (A2 != nullptr) ? 2 : 1;
    for (int pass = 0; pass < nPass; ++pass) {
        const float* __restrict__ A = pass ? A2 : A1;
        const unsigned short* __restrict__ WT = pass ? W2T : W1T;
        for (int k0 = 0; k0 < HH; k0 += 64) {
            float4 av[AC];
            #pragma unroll
            for (int c = 0; c < AC; ++c)
                av[c] = *(const float4*)(A + (size_t)(m0 + c*16 + am_row)*HH + k0 + am_col);
            short8v bv[4];
            #pragma unroll
            for (int i = 0; i < 4; ++i)
                bv[i] = *(const short8v*)(WT + (size_t)(n0 + i*32 + bm_row)*HH + k0 + bm_col);
            __syncthreads();
            #pragma unroll
            for (int c = 0; c < AC; ++c) {
                int r = c*16 + am_row;
                short4v h;
                h[0]=(short)f2bf(av[c].x); h[1]=(short)f2bf(av[c].y);
                h[2]=(short)f2bf(av[c].z); h[3]=(short)f2bf(av[c].w);
                int ba = r*128 + ((am_col*2) ^ ((r & 7) << 4));
                *(short4v*)&As[ba >> 1] = h;
            }
            #pragma unroll
            for (int i = 0; i < 4; ++i) {
                int r = i*32 + bm_row;
                int ba = r*128 + ((bm_col*2) ^ ((r & 7) << 4));
                *(short8v*)&Bs[ba >> 1] = bv[i];
            }
            __syncthreads();
            #pragma unroll
            for (int ks = 0; ks < 2; ++ks) {
                const int kb = ks*64 + l4*16;
                short8v af[FM], bf[4];
                #pragma unroll
                for (int fm = 0; fm < FM; ++fm) {
                    int row = wm*(FM*16) + fm*16 + l15;
                    af[fm] = *(const short8v*)&As[(row*128 + (kb ^ ((row & 7) << 4))) >> 1];
                }
                #pragma unroll
                for (int fn = 0; fn < 4; ++fn) {
                    int row = wn*64 + fn*16 + l15;
                    bf[fn] = *(const short8v*)&Bs[(row*128 + (kb ^ ((row & 7) << 4))) >> 1];
                }
                #pragma unroll
                for (int fm = 0; fm < FM; ++fm)
                    #pragma unroll
                    for (int fn = 0; fn < 4; ++fn)
                        acc[fm][fn] = __builtin_amdgcn_mfma_f32_16x16x32_bf16(af[fm], bf[fn], acc[fm][fn], 0, 0, 0);
            }
            __syncthreads();
        }
    }
    #pragma unroll
    for (int fn = 0; fn < 4; ++fn) {
        int col = n0 + wn*64 + fn*16 + l15;
        float bb = bias ? bias[col] : 0.f;
        #pragma unroll
        for (int fm = 0; fm < FM; ++fm) {
            int row0 = m0 + wm*(FM*16) + fm*16 + l4*4;
            #pragma unroll
            for (int j = 0; j < 4; ++j) {
                float v = acc[fm][fn][j] + bb;
                if (act) v = gelu_erf(v);
                C[(size_t)(row0 + j)*HH + col] = v;
            }
        }
    }
}

// ---------------------------------------------------------------- fused MFMA message GEMM v8
// m97 structure + rule-21 swizzle: LDS dest stays LINEAR (gload_lds requires it),
// the global SOURCE slot is pre-swizzled (csl = slot ^ row&7) and the ds_read
// applies the matching XOR -> logical data identical, bank conflicts gone
// (16-way -> 2-way free). adjS/wS overlay As post-loop: LDS = exactly 32KB.
__global__ __launch_bounds__(256, 3) void k_msg8(
    const unsigned short* __restrict__ relbf, const unsigned short* __restrict__ CkT,
    const float* __restrict__ dk, const float* __restrict__ eeW,
    const float* __restrict__ weight, const int* __restrict__ adj,
    float* __restrict__ agg)
{
    __shared__ alignas(16) unsigned short As[128*64];    // 16KB
    __shared__ alignas(16) unsigned short Bs[128*64];    // 16KB
    // post-loop overlays into As (dead after last MFMA):
    int*   adjS = (int*)As;             // [4][32]  512B
    float* wS   = (float*)(As + 256);   // [4][32]  512B
    const int tid = threadIdx.x;
    // bijective XCD swizzle: 3072 = 8 * 384, n-fastest logical order
    const int bid = blockIdx.x;
    const int L = (bid & 7) * 384 + (bid >> 3);
    const int mt = L / 6, nt = L - mt*6;
    const int n0 = nt * 128;
    const int m0 = mt * 128;
    const int be0 = mt * 4;              // 4 entities per block
    const int b = be0 >> 9;
    const int w = tid >> 6, lane = tid & 63;
    const int wm = w >> 1, wn = w & 1;
    const int l15 = lane & 15, l4 = lane >> 4;
    // gload_lds: chunk = 8 rows x 128B; lane l -> row crow=l>>3, phys slot l&7.
    // source slot pre-swizzled so phys layout is row-XOR-rotated:
    const int crow = lane >> 3;
    const int csl  = (lane & 7) ^ crow;      // (r&7)==crow since rbase%8==0

    f32x4 acc[4][4];
    #pragma unroll
    for (int i = 0; i < 4; ++i)
        #pragma unroll
        for (int j = 0; j < 4; ++j) acc[i][j] = (f32x4){0.f,0.f,0.f,0.f};

    for (int t = 0; t < 12; ++t) {
        const int k0 = t*64;
        #pragma unroll
        for (int c = 0; c < 4; ++c) {
            int rbase = w*32 + c*8;
            GLOAD_LDS16(relbf + (size_t)(m0 + rbase + crow)*HH + k0 + csl*8,
                        &As[rbase*64]);
            GLOAD_LDS16(CkT   + (size_t)(n0 + rbase + crow)*HH + k0 + csl*8,
                        &Bs[rbase*64]);
        }
        __syncthreads();    // compiler drains vmcnt before the barrier
        #pragma unroll
        for (int ks = 0; ks < 2; ++ks) {
            const int ko = ks*32 + l4*8;     // logical ushort offset in row
            short8v af[4], bf[4];
            #pragma unroll
            for (int fm = 0; fm < 4; ++fm) {
                int row = wm*64 + fm*16 + l15;
                af[fm] = *(const short8v*)&As[row*64 + (ko ^ ((row & 7) << 3))];
            }
            #pragma unroll
            for (int fn = 0; fn < 4; ++fn) {
                int row = wn*64 + fn*16 + l15;
                bf[fn] = *(const short8v*)&Bs[row*64 + (ko ^ ((row & 7) << 3))];
            }
            #pragma unroll
            for (int fm = 0; fm < 4; ++fm)
                #pragma unroll
                for (int fn = 0; fn < 4; ++fn)
                    acc[fm][fn] = __builtin_amdgcn_mfma_f32_16x16x32_bf16(af[fm], bf[fn], acc[fm][fn], 0, 0, 0);
        }
        __syncthreads();
    }

    // K-loop done; As dead -> overlay per-entity data
    if (tid < 128) {
        adjS[tid] = adj[be0*RR + tid];
        wS[tid]   = weight[be0*RR + tid];
    }
    __syncthreads();

    // epilogue: gather tail + dk, gelu, weight, reduce over r
    #pragma unroll
    for (int eh = 0; eh < 2; ++eh) {
        const int el = wm*2 + eh;
        const int be = be0 + el;
        #pragma unroll
        for (int fn = 0; fn < 4; ++fn) {
            int col = n0 + wn*64 + fn*16 + l15;
            float d = dk[col];
            float s = 0.f;
            #pragma unroll
            for (int fp = 0; fp < 2; ++fp) {
                const int fm = eh*2 + fp;
                #pragma unroll
                for (int j = 0; j < 4; ++j) {
                    int rr = fp*16 + l4*4 + j;
                    int tl = adjS[el*RR + rr];
                    float tail = eeW[((size_t)(b*EE_N + tl))*HH + col];
                    s += wS[el*RR + rr] * gelu_erf(acc[fm][fn][j] + tail + d);
                }
            }
            s += __shfl_xor(s, 16);
            s += __shfl_xor(s, 32);
            if (l4 == 0) agg[(size_t)be*HH + col] = s;
        }
    }
}

// ---------------------------------------------------------------- fused MFMA message GEMM v6 (fallback, r9-proven)
template<int FUSE>
__global__ __launch_bounds__(256, 3) void k_msg6(
    const float* __restrict__ rel, const unsigned short* __restrict__ CkT,
    const float* __restrict__ dk, const float* __restrict__ eeW,
    const float* __restrict__ weight_in, const int* __restrict__ adj,
    const float* __restrict__ wr1c, const float* __restrict__ qd,
    const float* __restrict__ am,
    float* __restrict__ agg, float* __restrict__ logit_out,
    float* __restrict__ weight_out)
{
    __shared__ alignas(16) unsigned short As[64*64];
    __shared__ alignas(16) unsigned short Bs[256*64];
    int*   adjS = (int*)As;
    float* wS   = (float*)(As + 128);
    float* lgS  = (float*)(As + 256);
    const int tid = threadIdx.x;
    const int bid = blockIdx.x;
    const int L = (bid & 7) * 384 + (bid >> 3);
    const int mt = L / 3, nt = L - mt*3;
    const int n0 = nt * 256;
    const int m0 = mt * 64;
    const int be0 = mt * 2;
    const int b = be0 >> 9;
    const int wn = tid >> 6, lane = tid & 63;
    const int l15 = lane & 15, l4 = lane >> 4;
    const int am_row = tid >> 4;
    const int am_col = (tid & 15) * 4;
    const int bm_row = tid >> 3;
    const int bm_col = (tid & 7) * 8;
    const float* apA = rel + (size_t)(m0 + am_row)*HH + am_col;
    const unsigned short* apB = CkT + (size_t)(n0 + bm_row)*HH + bm_col;
    f32x4 acc[4][4];
    #pragma unroll
    for (int i = 0; i < 4; ++i)
        #pragma unroll
        for (int j = 0; j < 4; ++j) acc[i][j] = (f32x4){0.f,0.f,0.f,0.f};
    float lg[4] = {0.f, 0.f, 0.f, 0.f};
    float4 av[4];
    short8v bv[8];
    #pragma unroll
    for (int c = 0; c < 4; ++c) av[c] = *(const float4*)(apA + (size_t)c*16*HH);
    #pragma unroll
    for (int i = 0; i < 8; ++i) bv[i] = *(const short8v*)(apB + (size_t)i*32*HH);
    for (int t = 0; t < 12; ++t) {
        const int k0 = t*64;
        #pragma unroll
        for (int c = 0; c < 4; ++c) {
            int r = c*16 + am_row;
            short4v h;
            h[0]=(short)f2bf(av[c].x); h[1]=(short)f2bf(av[c].y);
            h[2]=(short)f2bf(av[c].z); h[3]=(short)f2bf(av[c].w);
            int ba = r*128 + ((am_col*2) ^ ((r & 7) << 4));
            *(short4v*)&As[ba >> 1] = h;
        }
        #pragma unroll
        for (int i = 0; i < 8; ++i) {
            int r = i*32 + bm_row;
            int ba = r*128 + ((bm_col*2) ^ ((r & 7) << 4));
            *(short8v*)&Bs[ba >> 1] = bv[i];
        }
        if (FUSE) {
            float4 wv = *(const float4*)(wr1c + k0 + am_col);
            #pragma unroll
            for (int c = 0; c < 4; ++c)
                lg[c] += av[c].x*wv.x + av[c].y*wv.y + av[c].z*wv.z + av[c].w*wv.w;
        }
        if (t < 11) {
            #pragma unroll
            for (int c = 0; c < 4; ++c)
                av[c] = *(const float4*)(apA + (size_t)c*16*HH + k0 + 64);
            #pragma unroll
            for (int i = 0; i < 8; ++i)
                bv[i] = *(const short8v*)(apB + (size_t)i*32*HH + k0 + 64);
        }
        __syncthreads();
        #pragma unroll
        for (int ks = 0; ks < 2; ++ks) {
            const int kb = ks*64 + l4*16;
            short8v af[4], bf[4];
            #pragma unroll
            for (int fm = 0; fm < 4; ++fm) {
                int row = fm*16 + l15;
                af[fm] = *(const short8v*)&As[(row*128 + (kb ^ ((row & 7) << 4))) >> 1];
            }
            #pragma unroll
            for (int fn = 0; fn < 4; ++fn) {
                int row = wn*64 + fn*16 + l15;
                bf[fn] = *(const short8v*)&Bs[(row*128 + (kb ^ ((row & 7) << 4))) >> 1];
            }
            #pragma unroll
            for (int fm = 0; fm < 4; ++fm)
                #pragma unroll
                for (int fn = 0; fn < 4; ++fn)
                    acc[fm][fn] = __builtin_amdgcn_mfma_f32_16x16x32_bf16(af[fm], bf[fn], acc[fm][fn], 0, 0, 0);
        }
        __syncthreads();
    }
    if (tid < 64) adjS[tid] = adj[be0*RR + tid];
    if (!FUSE && tid < 64) wS[tid] = weight_in[be0*RR + tid];
    if (FUSE) {
        #pragma unroll
        for (int c = 0; c < 4; ++c) {
            lg[c] += __shfl_xor(lg[c], 1);
            lg[c] += __shfl_xor(lg[c], 2);
            lg[c] += __shfl_xor(lg[c], 4);
            lg[c] += __shfl_xor(lg[c], 8);
        }
        if ((tid & 15) == 0) {
            #pragma unroll
            for (int c = 0; c < 4; ++c) lgS[c*16 + am_row] = lg[c];
        }
        __syncthreads();
        if (tid < 64) {
            float amv = am[be0*RR + tid];
            float l = lgS[tid] + qd[b] + qd[BB] + (1.0f - amv) * NEGF;
            float mx = l;
            #pragma unroll
            for (int off = 16; off; off >>= 1) mx = fmaxf(mx, __shfl_xor(mx, off, 32));
            float e = expf(l - mx);
            float sm = e;
            #pragma unroll
            for (int off = 16; off; off >>= 1) sm += __shfl_xor(sm, off, 32);
            float wgt = amv * e / sm;
            wS[tid] = wgt;
            if (nt == 0) {
                logit_out[be0*RR + tid] = l;
                weight_out[be0*RR + tid] = wgt;
            }
        }
    }
    __syncthreads();
    #pragma unroll
    for (int eh = 0; eh < 2; ++eh) {
        const int be = be0 + eh;
        #pragma unroll
        for (int fn = 0; fn < 4; ++fn) {
            int col = n0 + wn*64 + fn*16 + l15;
            float d = dk[col];
            float s = 0.f;
            #pragma unroll
            for (int fp = 0; fp < 2; ++fp) {
                const int fm = eh*2 + fp;
                #pragma unroll
                for (int j = 0; j < 4; ++j) {
                    int rr = fp*16 + l4*4 + j;
                    int tl = adjS[eh*RR + rr];
                    float tail = eeW[((size_t)(b*EE_N + tl))*HH + col];
                    s += wS[eh*RR + rr] * gelu_erf(acc[fm][fn][j] + tail + d);
                }
            }
            s += __shfl_xor(s, 16);
            s += __shfl_xor(s, 32);
            if (l4 == 0) agg[(size_t)be*HH + col] = s;
        }
    }
}

// ---------------------------------------------------------------- ent_score + sdot
__global__ __launch_bounds__(256) void k_score(const float* __restrict__ ee,
                                               const float* __restrict__ SW,
                                               const float* __restrict__ SB,
                                               const float* __restrict__ NM,
                                               const float* __restrict__ q,
                                               float* __restrict__ score,
                                               float* __restrict__ sdot) {
    const int wid = threadIdx.x >> 6, lane = threadIdx.x & 63;
    const int row = blockIdx.x*4 + wid;
    const int b = row >> 9;
    const float* er = ee + (size_t)row*HH;
    const float* qr = q + b*HH;
    float a1 = 0.f, a2 = 0.f;
    #pragma unroll
    for (int p = 0; p < 3; ++p) {
        int i4 = (p*64 + lane) << 2;
        float4 e4 = *(const float4*)(er + i4);
        float4 s4 = *(const float4*)(SW + i4);
        float4 q4 = *(const float4*)(qr + i4);
        a1 += e4.x*s4.x + e4.y*s4.y + e4.z*s4.z + e4.w*s4.w;
        a2 += e4.x*q4.x + e4.y*q4.y + e4.z*q4.z + e4.w*q4.w;
    }
    for (int off = 32; off; off >>= 1) { a1 += __shfl_xor(a1, off); a2 += __shfl_xor(a2, off); }
    if (lane == 0) {
        score[row] = a1 + SB[0] + (1.0f - NM[row]) * NEGF;
        sdot[row] = a2;
    }
}

// ---------------------------------------------------------------- triple_sim
__global__ void k_triple(const float* __restrict__ sdot, const int* __restrict__ adj,
                         const float* __restrict__ logit, float* __restrict__ tri) {
    int idx = blockIdx.x*256 + threadIdx.x;
    int b = idx >> 14;
    int n = idx & 16383;
    int e = n >> 5;
    int a = adj[idx];
    tri[idx] = sdot[b*EE_N + e] + sdot[b*EE_N + a] + logit[idx];
}

// ================================================================ launch
extern "C" void kernel_launch(void* const* d_in, const int* in_sizes, int n_in,
                              void* d_out, int out_size, void* d_ws, size_t ws_size,
                              hipStream_t stream) {
    const float* QE  = (const float*)d_in[0];
    const float* QM  = (const float*)d_in[1];
    const float* ENT = (const float*)d_in[2];
    const float* REL = (const float*)d_in[3];
    const int*   ADJ = (const int*)d_in[4];
    const float* NM  = (const float*)d_in[5];
    const float* AM  = (const float*)d_in[6];
    const float* PW  = (const float*)d_in[7];
    const float* PB  = (const float*)d_in[8];
    const float* RW  = (const float*)d_in[9];
    const float* RB  = (const float*)d_in[10];
    const float* MW  = (const float*)d_in[11];
    const float* MB  = (const float*)d_in[12];
    const float* UW  = (const float*)d_in[13];
    const float* UB  = (const float*)d_in[14];
    const float* RSW = (const float*)d_in[15];
    const float* RSB = (const float*)d_in[16];
    const float* SW  = (const float*)d_in[17];
    const float* SB  = (const float*)d_in[18];

    float* out = (float*)d_out;
    float* ws  = (float*)d_ws;
    float* o_ee    = out;                       // [4,512,768]
    float* o_score = out + 1572864;             // [4,512]
    float* o_logit = out + 1574912;             // [4,512,32]
    float* o_tri   = out + 1640448;             // [4,16384]

    unsigned short* CkT0 = (unsigned short*)(ws + WS_CKT0);
    unsigned short* CkT1 = (unsigned short*)(ws + WS_CKT1);
    unsigned short* PWT  = (unsigned short*)(ws + WS_PWT);
    unsigned short* W0bT = (unsigned short*)(ws + WS_W0BT);
    unsigned short* W1bT = (unsigned short*)(ws + WS_W1BT);
    unsigned short* U0tT = (unsigned short*)(ws + WS_U0TT);
    unsigned short* U0bT = (unsigned short*)(ws + WS_U0BT);
    unsigned short* U1tT = (unsigned short*)(ws + WS_U1TT);
    unsigned short* U1bT = (unsigned short*)(ws + WS_U1BT);
    unsigned short* M0tT = (unsigned short*)(ws + WS_M0TT);
    unsigned short* M1tT = (unsigned short*)(ws + WS_M1TT);
    unsigned short* RELBF = (unsigned short*)(ws + WS_RELBF);

    const bool big = ws_size >= WS_NEED_BYTES;   // deterministic path choice

    const size_t HT = (size_t)2*HH*HH;          // per-hop stride in msg_W/upd_W
    const size_t BOT = (size_t)HH*HH;           // bottom-half offset

    // q path + small vectors
    k_qbar<<<BB, 256, 0, stream>>>(QE, QM, ws + WS_QBAR);
    gemm_f32<<<dim3(12,1), 256, 0, stream>>>(ws + WS_QBAR, PW, PB, ws + WS_Q, BB, HH, HH, 0);
    k_small2<<<193, 256, 0, stream>>>(RW, RB, RSW, RSB, ws + WS_Q, ws + WS_WR1C, ws + WS_QD);

    // batch-transpose the 9 static weights to bf16 [n][k]
    WPairs wp;
    wp.s[0] = PW;            wp.d[0] = PWT;
    wp.s[1] = MW + BOT;      wp.d[1] = W0bT;
    wp.s[2] = MW + HT + BOT; wp.d[2] = W1bT;
    wp.s[3] = UW;            wp.d[3] = U0tT;
    wp.s[4] = UW + BOT;      wp.d[4] = U0bT;
    wp.s[5] = UW + HT;       wp.d[5] = U1tT;
    wp.s[6] = UW + HT + BOT; wp.d[6] = U1bT;
    wp.s[7] = MW;            wp.d[7] = M0tT;
    wp.s[8] = MW + HT;       wp.d[8] = M1tT;
    k_w2bf<<<dim3(24,24,9), 256, 0, stream>>>(wp);

    // dk vectors from the transposed bf16 top-half message weights
    k_dk2<<<384, 256, 0, stream>>>(M0tT, M1tT, RB, MB, ws + WS_D0, ws + WS_D1);

    // composite message weights  C_k = rproj_W @ msg_W[k][:768,:]  (MFMA) -> CkT bf16
    gemm_bf16<32><<<dim3(6,24), 256, 0, stream>>>(RW, M0tT, nullptr, nullptr, nullptr,
                                                  ws + WS_C0, 0);
    gemm_bf16<32><<<dim3(6,24), 256, 0, stream>>>(RW, M1tT, nullptr, nullptr, nullptr,
                                                  ws + WS_C1, 0);
    k_ckt<<<dim3(24,24), 256, 0, stream>>>(ws + WS_C0, CkT0);
    k_ckt<<<dim3(24,24), 256, 0, stream>>>(ws + WS_C1, CkT1);

    // ee0 = entity_embedding @ proj_W + proj_b   (bf16 MFMA)
    gemm_bf16<32><<<dim3(6,64), 256, 0, stream>>>(ENT, PWT, nullptr, nullptr, PB,
                                                  ws + WS_EEA, 0);

    if (big) {
        // rel -> bf16 (+ fused logit), then softmax weights
        k_cvt<<<16384, 256, 0, stream>>>(REL, ws + WS_WR1C, ws + WS_QD, AM,
                                         RELBF, o_logit);
        k_softmax<<<2048, 64, 0, stream>>>(o_logit, AM, ws + WS_W);

        // hop 0
        gemm_bf16<32><<<dim3(6,64), 256, 0, stream>>>(ws + WS_EEA, W0bT, nullptr, nullptr, nullptr,
                                                      ws + WS_EEW, 0);
        k_msg8<<<3072, 256, 0, stream>>>(RELBF, CkT0, ws + WS_D0, ws + WS_EEW,
                                         ws + WS_W, ADJ, ws + WS_AGG);
        gemm_bf16<32><<<dim3(6,64), 256, 0, stream>>>(ws + WS_EEA, U0tT, ws + WS_AGG, U0bT, UB,
                                                      ws + WS_EEB, 1);
        // hop 1
        gemm_bf16<32><<<dim3(6,64), 256, 0, stream>>>(ws + WS_EEB, W1bT, nullptr, nullptr, nullptr,
                                                      ws + WS_EEW, 0);
        k_msg8<<<3072, 256, 0, stream>>>(RELBF, CkT1, ws + WS_D1, ws + WS_EEW,
                                         ws + WS_W, ADJ, ws + WS_AGG);
        gemm_bf16<32><<<dim3(6,64), 256, 0, stream>>>(ws + WS_EEB, U1tT, ws + WS_AGG, U1bT,
                                                      UB + HH, o_ee, 1);
    } else {
        // fallback: round-9 proven path (reg-staged k_msg6, fused logit)
        gemm_bf16<32><<<dim3(6,64), 256, 0, stream>>>(ws + WS_EEA, W0bT, nullptr, nullptr, nullptr,
                                                      ws + WS_EEW, 0);
        k_msg6<1><<<3072, 256, 0, stream>>>(REL, CkT0, ws + WS_D0, ws + WS_EEW,
                                            nullptr, ADJ, ws + WS_WR1C, ws + WS_QD, AM,
                                            ws + WS_AGG, o_logit, ws + WS_W);
        gemm_bf16<32><<<dim3(6,64), 256, 0, stream>>>(ws + WS_EEA, U0tT, ws + WS_AGG, U0bT, UB,
                                                      ws + WS_EEB, 1);
        gemm_bf16<32><<<dim3(6,64), 256, 0, stream>>>(ws + WS_EEB, W1bT, nullptr, nullptr, nullptr,
                                                      ws + WS_EEW, 0);
        k_msg6<0><<<3072, 256, 0, stream>>>(REL, CkT1, ws + WS_D1, ws + WS_EEW,
                                            ws + WS_W, ADJ, ws + WS_WR1C, ws + WS_QD, AM,
                                            ws + WS_AGG, nullptr, nullptr);
        gemm_bf16<32><<<dim3(6,64), 256, 0, stream>>>(ws + WS_EEB, U1tT, ws + WS_AGG, U1bT,
                                                      UB + HH, o_ee, 1);
    }

    // scores + triple_sim
    k_score<<<512, 256, 0, stream>>>(o_ee, SW, SB, NM, ws + WS_Q, o_score, ws + WS_SDOT);
    k_triple<<<256, 256, 0, stream>>>(ws + WS_SDOT, ADJ, o_logit, o_tri);
}